// Round 1
// baseline (195.396 us; speedup 1.0000x reference)
//
#include <hip/hip_runtime.h>

// Problem constants (fixed by the reference)
#define DDIM 128   // fixed embedding dim
#define SDIM 128   // sparse embedding dim
#define EDIM 128   // output dim
#define NKEYS 4
#define CVAL 64

// ---------------------------------------------------------------------------
// Kernel 1: scatter-max to find, per token, the winning (key, entry) that
// sets its sparse row. Priority = key*M + pos + 1 (later key > earlier key,
// later pos > earlier pos within a key == numpy last-write-wins).
// code = (priority << 8) | (key << 6) | val   (priority < 2^19 -> fits u32)
// code == 0  <=>  token has no sparse entry (row stays zero).
// ---------------------------------------------------------------------------
__global__ void scatter_max_kernel(const int* __restrict__ i0, const int* __restrict__ v0,
                                   const int* __restrict__ i1, const int* __restrict__ v1,
                                   const int* __restrict__ i2, const int* __restrict__ v2,
                                   const int* __restrict__ i3, const int* __restrict__ v3,
                                   unsigned* __restrict__ winner, int M) {
    int t = blockIdx.x * blockDim.x + threadIdx.x;
    if (t >= 4 * M) return;
    int key = t / M;
    int pos = t - key * M;
    const int* ip;
    const int* vp;
    switch (key) {
        case 0:  ip = i0; vp = v0; break;
        case 1:  ip = i1; vp = v1; break;
        case 2:  ip = i2; vp = v2; break;
        default: ip = i3; vp = v3; break;
    }
    int n = ip[pos];
    unsigned val = (unsigned)vp[pos];
    unsigned code = ((unsigned)(t + 1) << 8) | ((unsigned)key << 6) | val;
    atomicMax(winner + n, code);
}

// ---------------------------------------------------------------------------
// Kernel 2: Pfixed[v][e] = sum_d fixed_table[v][d] * W_fixed[d][e] + b[e]
// One block per v, 128 threads (one per e). Table row staged in LDS.
// ---------------------------------------------------------------------------
__global__ void build_pfixed(const float* __restrict__ tab, const float* __restrict__ W,
                             const float* __restrict__ b, float* __restrict__ P) {
    __shared__ float row[DDIM];
    int v = blockIdx.x;
    int e = threadIdx.x;
    row[e] = tab[v * DDIM + e];
    __syncthreads();
    float acc = b[e];
#pragma unroll 8
    for (int d = 0; d < DDIM; ++d)
        acc = fmaf(row[d], W[d * EDIM + e], acc);
    P[v * EDIM + e] = acc;
}

// ---------------------------------------------------------------------------
// Kernel 3: Psparse[key*64+val][e] = sum_d tab_key[val][d] * W_sparse[d][e]
// 256 blocks (key = bid>>6, val = bid&63), 128 threads each.
// ---------------------------------------------------------------------------
__global__ void build_psparse(const float* __restrict__ t0, const float* __restrict__ t1,
                              const float* __restrict__ t2, const float* __restrict__ t3,
                              const float* __restrict__ W, float* __restrict__ P) {
    __shared__ float row[SDIM];
    int bidx = blockIdx.x;            // 0..255
    int key = bidx >> 6;
    int val = bidx & 63;
    const float* t = (key == 0) ? t0 : (key == 1) ? t1 : (key == 2) ? t2 : t3;
    int e = threadIdx.x;
    row[e] = t[val * SDIM + e];
    __syncthreads();
    float acc = 0.f;
#pragma unroll 8
    for (int d = 0; d < SDIM; ++d)
        acc = fmaf(row[d], W[d * EDIM + e], acc);
    P[bidx * EDIM + e] = acc;
}

// ---------------------------------------------------------------------------
// Kernel 4 (dominant): out[n] = Pfixed[f[n]] + (winner[n] ? Psparse[code&255] : 0)
// 32 lanes per token row, float4 per lane -> coalesced 512B row writes.
// Grid-stride; memory-bound (~512 MB write + ~12 MB read).
// ---------------------------------------------------------------------------
__global__ void gather_out(const int* __restrict__ f, const unsigned* __restrict__ winner,
                           const float4* __restrict__ Pf, const float4* __restrict__ Ps,
                           float4* __restrict__ out, int total /* N*32 */) {
    int i = blockIdx.x * blockDim.x + threadIdx.x;
    int stride = gridDim.x * blockDim.x;
    for (; i < total; i += stride) {
        int n = i >> 5;          // token
        int c = i & 31;          // float4 column within row
        int v = f[n];
        unsigned w = winner[n];
        float4 r = Pf[v * 32 + c];
        if (w) {
            float4 s = Ps[(int)(w & 255u) * 32 + c];
            r.x += s.x; r.y += s.y; r.z += s.z; r.w += s.w;
        }
        out[i] = r;
    }
}

extern "C" void kernel_launch(void* const* d_in, const int* in_sizes, int n_in,
                              void* d_out, int out_size, void* d_ws, size_t ws_size,
                              hipStream_t stream) {
    // Inputs in setup_inputs() dict order:
    // 0: fixed_features [N] int32
    // 1..8: idx0,val0, idx1,val1, idx2,val2, idx3,val3  [M] int32 each
    // 9: fixed_table [V,128] f32; 10..13: tab0..3 [64,128] f32
    // 14: W_fixed [128,128]; 15: W_sparse [128,128]; 16: b [128]
    const int* f    = (const int*)d_in[0];
    const int* i0   = (const int*)d_in[1];
    const int* v0   = (const int*)d_in[2];
    const int* i1   = (const int*)d_in[3];
    const int* v1   = (const int*)d_in[4];
    const int* i2   = (const int*)d_in[5];
    const int* v2   = (const int*)d_in[6];
    const int* i3   = (const int*)d_in[7];
    const int* v3   = (const int*)d_in[8];
    const float* fixed_table = (const float*)d_in[9];
    const float* t0 = (const float*)d_in[10];
    const float* t1 = (const float*)d_in[11];
    const float* t2 = (const float*)d_in[12];
    const float* t3 = (const float*)d_in[13];
    const float* Wf = (const float*)d_in[14];
    const float* Ws = (const float*)d_in[15];
    const float* b  = (const float*)d_in[16];

    const int N = in_sizes[0];
    const int M = in_sizes[1];
    const int V = in_sizes[9] / DDIM;

    // Workspace layout: winner [N u32] | Pfixed [V*128 f32] | Psparse [256*128 f32]
    char* ws = (char*)d_ws;
    unsigned* winner = (unsigned*)ws;
    float* Pf = (float*)(ws + (size_t)N * sizeof(unsigned));
    float* Ps = Pf + (size_t)V * EDIM;

    hipMemsetAsync(winner, 0, (size_t)N * sizeof(unsigned), stream);

    int scatter_threads = 4 * M;
    scatter_max_kernel<<<(scatter_threads + 255) / 256, 256, 0, stream>>>(
        i0, v0, i1, v1, i2, v2, i3, v3, winner, M);

    build_pfixed<<<V, EDIM, 0, stream>>>(fixed_table, Wf, b, Pf);
    build_psparse<<<NKEYS * CVAL, EDIM, 0, stream>>>(t0, t1, t2, t3, Ws, Ps);

    int total = N * 32;  // N rows * 32 float4 per row
    int blocks = 4096;
    gather_out<<<blocks, 256, 0, stream>>>(f, winner,
                                           (const float4*)Pf, (const float4*)Ps,
                                           (float4*)d_out, total);
}